// Round 16
// baseline (995.412 us; speedup 1.0000x reference)
//
#include <hip/hip_runtime.h>

#define NN 50000
#define NE 800000
#define RR 8
#define BB 8
#define EPSV 1e-5f
#define SCAN_B ((NN + 255) / 256)   // 196
#define NGRP 64

typedef unsigned short bfu;
typedef __attribute__((ext_vector_type(8))) short bf16x8;
typedef __attribute__((ext_vector_type(4))) float f32x4;

__device__ inline float bf2f(bfu u) { return __uint_as_float(((unsigned)u) << 16); }
__device__ inline bfu f2bf(float f) {
    unsigned u = __float_as_uint(f);
    return (bfu)((u + 0x7fffu + ((u >> 16) & 1u)) >> 16);   // RTNE
}

#define NW1 36864L
#define NW2 36864L
#define NW3 18432L
#define NCV ((long)NN * 64)
#define NZ  (400000L + 50000L + 2L * NGRP * 128)

// ---------------- W packing: logical W[k][o] -> MFMA B-frag layout ----------------
__device__ inline void build_one(const float* __restrict__ comp, const float* __restrict__ bases,
                                 const float* __restrict__ root, bfu* __restrict__ Wp,
                                 int O, int idx) {
    int k = idx / O, o = idx % O;
    float val;
    if (k < 512) {
        int r = k >> 6, i = k & 63;
        val = 0.f;
#pragma unroll
        for (int b = 0; b < BB; ++b)
            val += comp[r * BB + b] * bases[(b * 64 + i) * O + o];
    } else {
        val = root[(k - 512) * O + o];
    }
    int kt = k >> 5, kk = k & 31;
    int lane = ((kk >> 3) << 4) | (o & 15);
    int pos = ((kt * (O / 16) + (o >> 4)) * 64 + lane) * 8 + (kk & 7);
    Wp[pos] = f2bf(val);
}

// ---------------- once: W builds + x->bf16 + zero (cnt|fill|stats1|stats2) ----------------
__global__ void prep(const float* __restrict__ c1, const float* __restrict__ b1,
                     const float* __restrict__ r1, bfu* __restrict__ Wp1,
                     const float* __restrict__ c2, const float* __restrict__ b2,
                     const float* __restrict__ r2, bfu* __restrict__ Wp2,
                     const float* __restrict__ c3, const float* __restrict__ b3,
                     const float* __restrict__ r3, bfu* __restrict__ Wp3,
                     const float* __restrict__ x, bfu* __restrict__ xb,
                     float* __restrict__ zbase) {
    long i = (long)blockIdx.x * blockDim.x + threadIdx.x;
    long stride = (long)gridDim.x * blockDim.x;
    const long tot = NW1 + NW2 + NW3 + NCV + NZ;
    for (; i < tot; i += stride) {
        if (i < NW1) build_one(c1, b1, r1, Wp1, 64, (int)i);
        else if (i < NW1 + NW2) build_one(c2, b2, r2, Wp2, 64, (int)(i - NW1));
        else if (i < NW1 + NW2 + NW3) build_one(c3, b3, r3, Wp3, 32, (int)(i - NW1 - NW2));
        else if (i < NW1 + NW2 + NW3 + NCV) { long k = i - NW1 - NW2 - NW3; xb[k] = f2bf(x[k]); }
        else zbase[i - (NW1 + NW2 + NW3 + NCV)] = 0.f;
    }
}

// ---------------- once: per-(dst,rel) counts, range-binned (8 ranges) ----------------
__global__ void edge_count(const int* __restrict__ ei, const int* __restrict__ et,
                           float* __restrict__ cnt) {
    int range = blockIdx.x >> 8;
    int lo = range * (NN / 8), hi = lo + NN / 8;
    int i = (blockIdx.x & 255) * 256 + threadIdx.x;
    for (int e = i; e < NE; e += 256 * 256) {
        int d = ei[NE + e];
        if (d >= lo && d < hi)
            atomicAdd(&cnt[(size_t)d * RR + et[e]], 1.0f);
    }
}

// ---------------- once: exclusive scan of degree -> offs ----------------
__global__ void scan1(const float* __restrict__ cnt, int* __restrict__ offs, int* __restrict__ bsum) {
    __shared__ int sh[256];
    int b = blockIdx.x, t = threadIdx.x;
    int i = b * 256 + t;
    int v = 0;
    if (i < NN) {
        float s = 0.f;
#pragma unroll
        for (int r = 0; r < RR; ++r) s += cnt[(size_t)i * RR + r];
        v = (int)s;
    }
    sh[t] = v;
    __syncthreads();
    for (int s = 1; s < 256; s <<= 1) {
        int tmp = (t >= s) ? sh[t - s] : 0;
        __syncthreads();
        sh[t] += tmp;
        __syncthreads();
    }
    if (i < NN) offs[i] = sh[t] - v;
    if (t == 255) bsum[b] = sh[255];
}

__global__ void scan2(int* __restrict__ bsum, int* __restrict__ offs) {
    if (threadIdx.x == 0 && blockIdx.x == 0) {
        int run = 0;
        for (int b = 0; b < SCAN_B; ++b) { int t = bsum[b]; bsum[b] = run; run += t; }
        offs[NN] = run;
    }
}

__global__ void scan3(int* __restrict__ offs, const int* __restrict__ bsum) {
    int b = blockIdx.x, t = threadIdx.x;
    int i = b * 256 + t;
    if (i < NN) offs[i] += bsum[b];
}

// ---------------- once: place edges dst-sorted; packed src<<7 | dloc<<3 | r ----------------
__global__ void place(const int* __restrict__ ei, const int* __restrict__ et,
                      const int* __restrict__ offs, int* __restrict__ fill,
                      unsigned* __restrict__ esrt) {
    int range = blockIdx.x >> 8;
    int lo = range * (NN / 8), hi = lo + NN / 8;
    int i = (blockIdx.x & 255) * 256 + threadIdx.x;
    for (int e = i; e < NE; e += 256 * 256) {
        int d = ei[NE + e];
        if (d >= lo && d < hi) {
            int pos = offs[d] + atomicAdd(&fill[d], 1);
            esrt[pos] = ((unsigned)ei[e] << 7) | ((unsigned)(d & 15) << 3) | (unsigned)et[e];
        }
    }
}

// ---------------- fused per layer: EDGE-PARALLEL LDS aggregate -> A-frags -> MFMA GEMM ----------------
// Block = 16 nodes (contiguous esrt range). 4 waves split the range by EDGE COUNT.
// Per edge: readlane src (SGPR) -> coalesced 128B gather -> ds_add_f32 into accL[dloc*8+r][lane].
// Edges are fully independent (no accumulator chain, no relation dispatch).
template <int O, bool RELU, bool STATS>
__global__ __launch_bounds__(256) void agg_gemm(const int* __restrict__ offs,
                                                const unsigned* __restrict__ esrt,
                                                const float* __restrict__ cnt,
                                                const bfu* __restrict__ xb,
                                                const bfu* __restrict__ Wp,
                                                const float* __restrict__ bias,
                                                float* __restrict__ outp,
                                                float* __restrict__ stats) {
    constexpr int CT = O / 16;
    __shared__ float accL[128 * 64];                 // [dloc*8+r][lane]  32KB
    __shared__ bfu Af[1152 * 8];                     // MFMA A-frags     18KB
    int wave = threadIdx.x >> 6, lane = threadIdx.x & 63;
    int n0 = blockIdx.x * 16;

    for (int i = threadIdx.x; i < 128 * 64; i += 256) accL[i] = 0.f;
    __syncthreads();

    int e0 = offs[n0], e1 = offs[n0 + 16];
    int per = (e1 - e0 + 3) >> 2;
    int jw0 = e0 + wave * per;
    int jw1 = jw0 + per; if (jw1 > e1) jw1 = e1;
    if (jw0 > e1) jw0 = e1;

    int j = jw0;
    for (; j + 16 <= jw1; j += 16) {
        unsigned mye = esrt[j + (lane & 15)];        // 16 packed words, replicated 4x
#pragma unroll
        for (int k = 0; k < 16; ++k) {
            int u = __builtin_amdgcn_readlane((int)mye, k);
            unsigned src = ((unsigned)u) >> 7;
            float v = bf2f(xb[(size_t)src * 64 + lane]);
            atomicAdd(&accL[(u & 127) * 64 + lane], v);
        }
    }
    for (; j < jw1; ++j) {
        int u = __builtin_amdgcn_readfirstlane((int)esrt[j]);
        unsigned src = ((unsigned)u) >> 7;
        float v = bf2f(xb[(size_t)src * 64 + lane]);
        atomicAdd(&accL[(u & 127) * 64 + lane], v);
    }
    __syncthreads();

    int c = lane;
    int swz_lo = ((c >> 3) & 3) << 4;
    // normalize + write A-frags: 128 (dloc,r) rows; wave handles 32
#pragma unroll 4
    for (int row = wave * 32; row < wave * 32 + 32; ++row) {
        int dloc = row >> 3, r = row & 7;
        float cn = cnt[(size_t)(n0 + dloc) * RR + r];
        float v = accL[row * 64 + lane] / fmaxf(cn, 1.f);
        bfu bv = f2bf(v);
        int g = (2 * r + (c >> 5)) * 64 + (dloc | swz_lo);
        int gs = g ^ ((g >> 3) & 7) ^ ((g >> 6) & 7);
        Af[gs * 8 + (c & 7)] = bv;
    }
    // root-input columns k=512+c (kt=16,17): 16 rows; wave handles 4
#pragma unroll
    for (int dloc = wave * 4; dloc < wave * 4 + 4; ++dloc) {
        bfu bv = xb[(size_t)(n0 + dloc) * 64 + lane];
        int g = (16 + (c >> 5)) * 64 + (dloc | swz_lo);
        int gs = g ^ ((g >> 3) & 7) ^ ((g >> 6) & 7);
        Af[gs * 8 + (c & 7)] = bv;
    }
    __syncthreads();

    int ct = wave;
    if (CT == 4 || ct < CT) {
        f32x4 acc = (f32x4){0.f, 0.f, 0.f, 0.f};
#pragma unroll
        for (int kt = 0; kt < 18; ++kt) {
            int g = kt * 64 + lane;
            int gs = g ^ ((g >> 3) & 7) ^ ((g >> 6) & 7);
            bf16x8 af = *(const bf16x8*)&Af[gs * 8];
            bf16x8 bfv = *(const bf16x8*)&Wp[((size_t)(kt * CT + ct) * 64 + lane) * 8];
            acc = __builtin_amdgcn_mfma_f32_16x16x32_bf16(af, bfv, acc, 0, 0, 0);
        }
        int col = ct * 16 + (lane & 15);
        float b = bias[col];
        float ssum = 0.f, sq = 0.f;
#pragma unroll
        for (int jj = 0; jj < 4; ++jj) {
            int row = (lane >> 4) * 4 + jj;
            float v = acc[jj] + b;
            if (RELU) v = fmaxf(v, 0.f);
            outp[(size_t)(n0 + row) * O + col] = v;
            if (STATS) { ssum += v; sq += v * v; }
        }
        if (STATS) {
            ssum += __shfl_xor(ssum, 16); ssum += __shfl_xor(ssum, 32);
            sq   += __shfl_xor(sq, 16);   sq   += __shfl_xor(sq, 32);
            if ((lane >> 4) == 0) {
                int g = blockIdx.x & (NGRP - 1);
                atomicAdd(&stats[g * 128 + col], ssum);
                atomicAdd(&stats[g * 128 + 64 + col], sq);
            }
        }
    }
}

// ---------------- BN: finalize (redundant per block) + apply, fused ----------------
template <bool HASRES>
__global__ __launch_bounds__(256) void bn_apply(const float* __restrict__ y,
                                                const float* __restrict__ stats,
                                                const float* __restrict__ gamma,
                                                const float* __restrict__ beta,
                                                const bfu* __restrict__ resb,
                                                bfu* __restrict__ hb) {
    __shared__ float sc[128];
    int t = threadIdx.x;
    if (t < 64) {
        float s = 0.f, q = 0.f;
        for (int g = 0; g < NGRP; ++g) {
            s += stats[g * 128 + t];
            q += stats[g * 128 + 64 + t];
        }
        float mu = s / (float)NN;
        float var = q / (float)NN - mu * mu;
        float scale = gamma[t] * rsqrtf(var + EPSV);
        sc[t] = scale;
        sc[64 + t] = beta[t] - mu * scale;
    }
    __syncthreads();
    long tot = (long)NN * 64;
    long stride = (long)gridDim.x * blockDim.x;
    for (long i = (long)blockIdx.x * blockDim.x + threadIdx.x; i < tot; i += stride) {
        int cc = (int)(i & 63);
        float v = y[i] * sc[cc] + sc[64 + cc];
        if (HASRES) v += bf2f(resb[i]);
        hb[i] = f2bf(v);
    }
}

extern "C" void kernel_launch(void* const* d_in, const int* in_sizes, int n_in,
                              void* d_out, int out_size, void* d_ws, size_t ws_size,
                              hipStream_t stream) {
    const float* x      = (const float*)d_in[0];
    const int*   ei     = (const int*)d_in[1];
    const int*   et     = (const int*)d_in[2];
    const float* comp1  = (const float*)d_in[3];
    const float* bases1 = (const float*)d_in[4];
    const float* root1  = (const float*)d_in[5];
    const float* bias1  = (const float*)d_in[6];
    const float* comp2  = (const float*)d_in[7];
    const float* bases2 = (const float*)d_in[8];
    const float* root2  = (const float*)d_in[9];
    const float* bias2  = (const float*)d_in[10];
    const float* comp3  = (const float*)d_in[11];
    const float* bases3 = (const float*)d_in[12];
    const float* root3  = (const float*)d_in[13];
    const float* bias3  = (const float*)d_in[14];
    const float* gamma1 = (const float*)d_in[15];
    const float* beta1  = (const float*)d_in[16];
    const float* gamma2 = (const float*)d_in[17];
    const float* beta2  = (const float*)d_in[18];
    float* out = (float*)d_out;

    float* ws = (float*)d_ws;
    size_t off = 0;
    bfu* Wp1 = (bfu*)(ws + off); off += 18432;                // 36864 bf16
    bfu* Wp2 = (bfu*)(ws + off); off += 18432;
    bfu* Wp3 = (bfu*)(ws + off); off += 9216;                 // 18432 bf16
    float* cnt    = ws + off; off += (size_t)NN * RR;         // -- zero region start
    int*   fill   = (int*)(ws + off); off += NN;
    float* stats1 = ws + off; off += NGRP * 128;
    float* stats2 = ws + off; off += NGRP * 128;              // -- zero region end
    float* y  = ws + off; off += (size_t)NN * 64;
    bfu* xb   = (bfu*)(ws + off); off += (size_t)NN * 32;
    bfu* h1b  = (bfu*)(ws + off); off += (size_t)NN * 32;
    bfu* hb   = (bfu*)(ws + off); off += (size_t)NN * 32;
    int* offs = (int*)(ws + off); off += NN + 4;
    int* bsum = (int*)(ws + off); off += 256;
    unsigned* esrt = (unsigned*)(ws + off); off += NE;

    // ---- once: prep (W pack + bf16 cvt + zeros), counts, CSR ----
    prep<<<dim3(2048), dim3(256), 0, stream>>>(comp1, bases1, root1, Wp1,
                                               comp2, bases2, root2, Wp2,
                                               comp3, bases3, root3, Wp3,
                                               x, xb, cnt);
    edge_count<<<dim3(2048), dim3(256), 0, stream>>>(ei, et, cnt);
    scan1<<<dim3(SCAN_B), dim3(256), 0, stream>>>(cnt, offs, bsum);
    scan2<<<dim3(1), dim3(64), 0, stream>>>(bsum, offs);
    scan3<<<dim3(SCAN_B), dim3(256), 0, stream>>>(offs, bsum);
    place<<<dim3(2048), dim3(256), 0, stream>>>(ei, et, offs, fill, esrt);

    // ---- layer 1 ----
    agg_gemm<64, true, true><<<dim3(NN / 16), dim3(256), 0, stream>>>(offs, esrt, cnt, xb, Wp1, bias1, y, stats1);
    bn_apply<false><<<dim3(256), dim3(256), 0, stream>>>(y, stats1, gamma1, beta1, nullptr, h1b);

    // ---- layer 2 ----
    agg_gemm<64, true, true><<<dim3(NN / 16), dim3(256), 0, stream>>>(offs, esrt, cnt, h1b, Wp2, bias2, y, stats2);
    bn_apply<true><<<dim3(256), dim3(256), 0, stream>>>(y, stats2, gamma2, beta2, h1b, hb);

    // ---- layer 3 (output) ----
    agg_gemm<32, false, false><<<dim3(NN / 16), dim3(256), 0, stream>>>(offs, esrt, cnt, hb, Wp3, bias3, out, nullptr);
}